// Round 1
// baseline (766.548 us; speedup 1.0000x reference)
//
#include <hip/hip_runtime.h>
#include <hip/hip_bf16.h>
#include <stdint.h>
#include <stddef.h>

#define BATCH 512
#define RSZ   196
#define DV    1024
#define DH    512
#define DA    256

typedef short short8 __attribute__((ext_vector_type(8)));
typedef float f32x4 __attribute__((ext_vector_type(4)));

static __device__ __forceinline__ short f2bf(float f) {
    union { float f; unsigned u; } x; x.f = f;
    unsigned r = x.u + 0x7fffu + ((x.u >> 16) & 1u);  // RNE
    return (short)(r >> 16);
}

// packed fp32x2 -> bf16x2 (v_cvt_pk_bf16_f32 on gfx950), returned as int
static __device__ __forceinline__ int pk2(float x, float y) {
    float2 f; f.x = x; f.y = y;
    __hip_bfloat162 h = __float22bfloat162_rn(f);
    int r; __builtin_memcpy(&r, &h, 4); return r;
}

// ---------------- kernel 0: fused prep (unchanged)
//  blocks [0,64):   Wv [1024][256] fp32 -> WvT [256][1024] bf16 (16 k-rows per block)
//  blocks [64,576): H[b][a] = hs[b]@Wh[:,a] + bh[a] + bv[a]
__global__ __launch_bounds__(256) void k_prep(const float* __restrict__ Wv,
                                              const float* __restrict__ hs,
                                              const float* __restrict__ Wh,
                                              const float* __restrict__ bh,
                                              const float* __restrict__ bv,
                                              short* __restrict__ WvT,
                                              float* __restrict__ H) {
    int tid = threadIdx.x;
    if (blockIdx.x < 64) {
        __shared__ short tile[16][DA];
        int k0 = blockIdx.x * 16;
#pragma unroll
        for (int r = 0; r < 16; ++r)
            tile[r][tid] = f2bf(Wv[(size_t)(k0 + r) * DA + tid]);
        __syncthreads();
        short o[16];
#pragma unroll
        for (int r = 0; r < 16; ++r) o[r] = tile[r][tid];
        *(short8*)&WvT[(size_t)tid * DV + k0]     = *(short8*)&o[0];
        *(short8*)&WvT[(size_t)tid * DV + k0 + 8] = *(short8*)&o[8];
    } else {
        __shared__ float sh[DH];
        int b = blockIdx.x - 64, a = tid;
        sh[a]       = hs[b * DH + a];
        sh[a + 256] = hs[b * DH + 256 + a];
        __syncthreads();
        float acc = 0.f;
#pragma unroll 8
        for (int k = 0; k < DH; ++k) acc += sh[k] * Wh[k * DA + a];
        H[b * DA + a] = acc + bh[a] + bv[a];
    }
}

// ---------------- kernel 1: fully-fused flash-style attention
// One block per batch, 4 waves (one per 64-col N chunk).
// New structure vs prior round:
//   * B (WvT) loaded L2 -> registers, double-buffered one iter ahead (no Bs LDS,
//     no global_load_lds, no vmcnt-drain at barriers).
//   * A staged to double-buffered LDS via regs; ONE raw s_barrier per K-iter with
//     lgkmcnt(0)-only wait, so all global loads stay in flight across barriers.
//   * O-accumulate (prev tile, 4 rows/iter) folded into the K-loop: loads issued
//     before the MFMA cluster, FMAs after -> vf re-read hides under MFMA.
#define BK  64
#define LDA 72

#define BAR() do { asm volatile("s_waitcnt lgkmcnt(0)" ::: "memory"); \
                   __builtin_amdgcn_s_barrier(); } while (0)

__global__ __launch_bounds__(256, 2) void k_fused(const float* __restrict__ vf,
                                                  const short* __restrict__ WvT,
                                                  const float* __restrict__ H,
                                                  const float* __restrict__ Wa,
                                                  const float* __restrict__ ba,
                                                  float* __restrict__ out) {
    __shared__ short As[2][64 * LDA];   // 18.4 KB double-buffered A tile
    __shared__ float sH[DA];
    __shared__ float sWa[DA];
    __shared__ float red[64][4];
    __shared__ float sp[64];            // tile p-values
    __shared__ float sml[4];            // [0]=running m, [1]=running l, [2]=alpha

    const int tid = threadIdx.x;
    const int l   = tid & 63;
    const int w   = tid >> 6;           // wave 0..3 -> N-chunk w*64
    const int ln  = l & 15;
    const int q   = l >> 4;
    const int b   = blockIdx.x;

    sH[tid]  = H[b * DA + tid];
    sWa[tid] = Wa[tid];
    if (tid == 0) { sml[0] = -1e30f; sml[1] = 0.f; }

    // A staging: thread -> row ar (0..63), 16 cols at ac (within BK chunk)
    const int ar = tid >> 2;
    const int ac = (tid & 3) * 16;
    const float* aprow = vf + (size_t)b * RSZ * DV;
    // B fragment base: lane reads WvT[(w*64 + j*16 + ln)*DV + kt + kk*32 + q*8]
    const short* bp = WvT + (size_t)(w * 64 + ln) * DV + q * 8;

    float4 O = {0.f, 0.f, 0.f, 0.f};    // each thread owns cols 4*tid..4*tid+3
    const float baS = ba[0];

    float4 g0, g1, g2, g3;              // A staging regs (raw fp32)
    short8 B0[8], B1[8];                // B double-buffer (j*2+kk)

    auto issueA = [&](int t, int kt) {
        int nr = (t < 3) ? 64 : 4;
        if (ar < nr) {
            const float4* p4 = (const float4*)(aprow + ((size_t)(t * 64 + ar)) * DV + ac) + (kt >> 2);
            g0 = p4[0]; g1 = p4[1]; g2 = p4[2]; g3 = p4[3];
        } else {
            g0 = g1 = g2 = g3 = (float4){0.f, 0.f, 0.f, 0.f};
        }
    };
    auto loadB = [&](short8 (&Bv)[8], int kt) {
#pragma unroll
        for (int j = 0; j < 4; ++j)
#pragma unroll
            for (int kk = 0; kk < 2; ++kk)
                Bv[j * 2 + kk] = *(const short8*)(bp + (size_t)j * 16 * DV + kt + kk * 32);
    };
    auto stageA = [&](int buf) {
        union { short8 v; int i[4]; } u0, u1;
        u0.i[0] = pk2(g0.x, g0.y); u0.i[1] = pk2(g0.z, g0.w);
        u0.i[2] = pk2(g1.x, g1.y); u0.i[3] = pk2(g1.z, g1.w);
        u1.i[0] = pk2(g2.x, g2.y); u1.i[1] = pk2(g2.z, g2.w);
        u1.i[2] = pk2(g3.x, g3.y); u1.i[3] = pk2(g3.z, g3.w);
        short* awr = &As[buf][ar * LDA + ac];
        *(short8*)&awr[0] = u0.v;
        *(short8*)&awr[8] = u1.v;
    };

    // prologue: A(0,0) -> As[0], B(0) -> B0
    issueA(0, 0);
    loadB(B0, 0);
    stageA(0);
    __syncthreads();                    // also publishes sH/sWa/sml init

    for (int t = 0; t < 4; ++t) {
        const int micnt = (t < 3) ? 4 : 1;
        f32x4 acc[4][4];
#pragma unroll
        for (int i = 0; i < 4; ++i)
#pragma unroll
            for (int j = 0; j < 4; ++j) acc[i][j] = (f32x4){0.f, 0.f, 0.f, 0.f};

        auto body = [&](int kt, int cur, short8 (&Bc)[8], short8 (&Bn)[8]) {
            const int  ktn     = kt + BK;
            const bool tileEnd = (ktn == DV);
            const int  tn      = tileEnd ? t + 1 : t;
            const int  kn      = tileEnd ? 0 : ktn;
            // issue next-iter A/B loads early (stay in flight across BAR)
            if (tn < 4) { issueA(tn, kn); loadB(Bn, kn); }
            // prev-tile O-accum: issue loads before MFMA cluster
            float4 v0, v1, v2, v3; float p0, p1, p2, p3;
            const int rb = (kt >> 6) * 4;
            if (t > 0) {
                const float4* vp = (const float4*)(aprow + ((size_t)((t - 1) * 64 + rb)) * DV) + tid;
                v0 = vp[0 * (DV / 4)]; v1 = vp[1 * (DV / 4)];
                v2 = vp[2 * (DV / 4)]; v3 = vp[3 * (DV / 4)];
                p0 = sp[rb]; p1 = sp[rb + 1]; p2 = sp[rb + 2]; p3 = sp[rb + 3];
            }
            // MFMA cluster from As[cur] x Bc
#pragma unroll
            for (int kk = 0; kk < 2; ++kk) {
#pragma unroll
                for (int i = 0; i < 4; ++i) {
                    if (i < micnt) {
                        short8 afr = *(short8*)&As[cur][(i * 16 + ln) * LDA + kk * 32 + q * 8];
#pragma unroll
                        for (int j = 0; j < 4; ++j)
                            acc[i][j] = __builtin_amdgcn_mfma_f32_16x16x32_bf16(
                                afr, Bc[j * 2 + kk], acc[i][j], 0, 0, 0);
                    }
                }
            }
            // O-accum FMAs after MFMA (loads' latency hidden)
            if (t > 0) {
                O.x += p0 * v0.x + p1 * v1.x + p2 * v2.x + p3 * v3.x;
                O.y += p0 * v0.y + p1 * v1.y + p2 * v2.y + p3 * v3.y;
                O.z += p0 * v0.z + p1 * v1.z + p2 * v2.z + p3 * v3.z;
                O.w += p0 * v0.w + p1 * v1.w + p2 * v2.w + p3 * v3.w;
            }
            // stage next A into the other LDS buffer (incl. next tile's kt=0)
            if (tn < 4) stageA(cur ^ 1);
            BAR();                      // lgkmcnt-only: global loads stay in flight
        };

        for (int k2 = 0; k2 < DV; k2 += 2 * BK) {
            body(k2,      0, B0, B1);
            body(k2 + BK, 1, B1, B0);
        }

        // ---- epilogue: relu(acc + H) * Wa, reduce over 256 cols -> red[row][w]
#pragma unroll
        for (int i = 0; i < 4; ++i) {
            if (i < micnt) {
#pragma unroll
                for (int r = 0; r < 4; ++r) {
                    int row = i * 16 + q * 4 + r;
                    float p = 0.f;
#pragma unroll
                    for (int j = 0; j < 4; ++j) {
                        int a   = w * 64 + j * 16 + ln;
                        float v = acc[i][j][r] + sH[a];
                        p += fmaxf(v, 0.f) * sWa[a];
                    }
                    p += __shfl_xor(p, 1);
                    p += __shfl_xor(p, 2);
                    p += __shfl_xor(p, 4);
                    p += __shfl_xor(p, 8);
                    if (ln == 0) red[row][w] = p;
                }
            }
        }
        __syncthreads();

        // ---- online softmax update (wave 0)
        const int nrows = (t < 3) ? 64 : 4;
        if (tid < 64) {
            float s = (tid < nrows)
                    ? (red[tid][0] + red[tid][1] + red[tid][2] + red[tid][3] + baS)
                    : -1e30f;
            float tm = s;
#pragma unroll
            for (int mk = 32; mk >= 1; mk >>= 1) tm = fmaxf(tm, __shfl_xor(tm, mk));
            float m_old = sml[0];
            float m_new = fmaxf(m_old, tm);
            float p = (tid < nrows) ? expf(s - m_new) : 0.f;
            sp[tid] = p;
            float ls = p;
#pragma unroll
            for (int mk = 32; mk >= 1; mk >>= 1) ls += __shfl_xor(ls, mk);
            if (tid == 0) {
                float alpha = expf(m_old - m_new);
                sml[2] = alpha;
                sml[1] = sml[1] * alpha + ls;
                sml[0] = m_new;
            }
        }
        __syncthreads();

        // rescale running O by this tile's alpha; tile-t rows accumulate during
        // tile t+1's K-loop (or standalone below for the tail tile)
        float alpha = sml[2];
        O.x *= alpha; O.y *= alpha; O.z *= alpha; O.w *= alpha;
    }

    // ---- standalone accumulation of tail tile rows (192..195)
    {
        const float4* vp = (const float4*)(aprow + (size_t)192 * DV) + tid;
        float4 v0 = vp[0 * (DV / 4)], v1 = vp[1 * (DV / 4)];
        float4 v2 = vp[2 * (DV / 4)], v3 = vp[3 * (DV / 4)];
        float p0 = sp[0], p1 = sp[1], p2 = sp[2], p3 = sp[3];
        O.x += p0 * v0.x + p1 * v1.x + p2 * v2.x + p3 * v3.x;
        O.y += p0 * v0.y + p1 * v1.y + p2 * v2.y + p3 * v3.y;
        O.z += p0 * v0.z + p1 * v1.z + p2 * v2.z + p3 * v3.z;
        O.w += p0 * v0.w + p1 * v1.w + p2 * v2.w + p3 * v3.w;
    }

    float invl = 1.f / sml[1];
    float4 res = {O.x * invl, O.y * invl, O.z * invl, O.w * invl};
    ((float4*)(out + (size_t)b * DV))[tid] = res;
}

extern "C" void kernel_launch(void* const* d_in, const int* in_sizes, int n_in,
                              void* d_out, int out_size, void* d_ws, size_t ws_size,
                              hipStream_t stream) {
    const float* vf = (const float*)d_in[0];   // [512,196,1024]
    const float* hs = (const float*)d_in[1];   // [512,512]
    const float* Wv = (const float*)d_in[2];   // [1024,256]
    const float* bv = (const float*)d_in[3];   // [256]
    const float* Wh = (const float*)d_in[4];   // [512,256]
    const float* bh = (const float*)d_in[5];   // [256]
    const float* Wa = (const float*)d_in[6];   // [256]
    const float* ba = (const float*)d_in[7];   // scalar
    float* out = (float*)d_out;                // [512,1024]

    char* ws = (char*)d_ws;
    short* WvT = (short*)(ws);                 // 512 KB
    float* H   = (float*)(ws + (512 << 10));   // 512 KB

    k_prep<<<576, 256, 0, stream>>>(Wv, hs, Wh, bh, bv, WvT, H);
    k_fused<<<BATCH, 256, 0, stream>>>(vf, WvT, H, Wa, ba, out);
}